// Round 5
// baseline (136.746 us; speedup 1.0000x reference)
//
#include <hip/hip_runtime.h>
#include <math.h>

// Problem constants (fixed by the reference)
#define BD   128      // batch == hidden
#define ID   1024     // img dim
#define TD   1024     // txt dim
#define NE   32768    // edges
#define HD   128      // hidden

// ---------------------------------------------------------------------------
// K_A: H precompute. 256 blocks x 256 threads, 8 feature-rows per block.
//   HimgT[i,h] = sum_b img[b,i]*W1[h,b]       (+ b1[h] folded in)
//   HtxtT[t,h] = sum_b text[b,t]*W1[h,128+b]
// W1-side staged TRANSPOSED into LDS (stride 129, conflict-free); S-tile via
// float4. Inner loop per b: 1 conflict-free ds_read + 1 broadcast ds_read_b128
// + 4 FMA.
// ---------------------------------------------------------------------------
__global__ __launch_bounds__(256) void h_kernel(
    const float* __restrict__ img, const float* __restrict__ text,
    const float* __restrict__ W1, const float* __restrict__ b1,
    float* __restrict__ HimgT, float* __restrict__ HtxtT)
{
    __shared__ __align__(16) float Wl[64 * 129];  // 33 KB: Wl[b'*129+h]
    __shared__ __align__(16) float Sl[128 * 8];   // 4 KB:  Sl[b*8+il]
    const int blk = blockIdx.x, tid = threadIdx.x;
    const int side = blk >> 7;            // 0: img, 1: txt (128 blocks each)
    const int i0 = (blk & 127) * 8;
    const float* S = side ? text : img;
    float* Dst = side ? HtxtT : HimgT;
    const int soff = side * 128;

    {   // stage S tile: 128 rows x 8 floats = 256 float4 (coalesced)
        int b = tid >> 1, q = tid & 1;
        ((float4*)Sl)[tid] = *(const float4*)(S + b * 1024 + i0 + q * 4);
    }

    const int h = tid & 127, iq = tid >> 7;
    float acc[4] = {0.f, 0.f, 0.f, 0.f};
    #pragma unroll
    for (int half = 0; half < 2; half++) {
        __syncthreads();   // Sl ready (1st) / Wl no longer read (2nd)
        for (int idx = tid; idx < 8192; idx += 256) {
            int hh = idx >> 6, bb = idx & 63;
            Wl[bb * 129 + hh] = W1[hh * 256 + soff + half * 64 + bb];
        }
        __syncthreads();
        #pragma unroll 8
        for (int bb = 0; bb < 64; bb++) {
            int b = half * 64 + bb;
            float w = Wl[bb * 129 + h];                        // conflict-free
            float4 s4 = *(const float4*)(Sl + b * 8 + iq * 4); // broadcast
            acc[0] += s4.x * w; acc[1] += s4.y * w;
            acc[2] += s4.z * w; acc[3] += s4.w * w;
        }
    }
    float bias = side ? 0.f : b1[h];      // fold b1 into img side
    #pragma unroll
    for (int r = 0; r < 4; r++)
        Dst[(i0 + iq * 4 + r) * 128 + h] = acc[r] + bias;   // coalesced
}

// ---------------------------------------------------------------------------
// K_B: a = sigmoid(w2 . relu(HimgT[src]+HtxtT[tgt]) + b2), scattered into the
// DENSE pattern matrices: A[src,tgt] = a and At[tgt,src] = a (pre-zeroed).
// 2048 blocks x 256 thr = 8192 waves, 4 edges per wave.
// ---------------------------------------------------------------------------
__global__ __launch_bounds__(256) void edge_kernel(
    const int* __restrict__ src, const int* __restrict__ tgt,
    const float* __restrict__ HimgT, const float* __restrict__ HtxtT,
    const float* __restrict__ w2, const float* __restrict__ b2,
    float* __restrict__ A, float* __restrict__ At)
{
    const int lane = threadIdx.x & 63;
    const int wgid = blockIdx.x * 4 + (threadIdx.x >> 6);   // 0..8191
    const float w2a = w2[lane], w2b = w2[lane + 64];
    const float b2v = b2[0];
    #pragma unroll
    for (int k = 0; k < 4; k++) {
        int e = wgid * 4 + k;
        int s0 = src[e], t0 = tgt[e];
        const float* Hi = HimgT + s0 * 128;
        const float* Ht = HtxtT + t0 * 128;
        float v1 = Hi[lane]      + Ht[lane];
        float v2 = Hi[lane + 64] + Ht[lane + 64];
        float x = fmaxf(v1, 0.f) * w2a + fmaxf(v2, 0.f) * w2b;
        #pragma unroll
        for (int off = 32; off > 0; off >>= 1)
            x += __shfl_xor(x, off, 64);
        if (lane == 0) {
            float av = 1.f / (1.f + expf(-(x + b2v)));
            A [s0 * 1024 + t0] = av;      // unique (src,tgt): plain stores
            At[t0 * 1024 + s0] = av;
        }
    }
}

// ---------------------------------------------------------------------------
// K_C: dense GEMM replaces the atomic scatter (R3/R4: 47 us, DS-pipe bound).
//   att_img [b,i] = sum_k At[k,i] * text[b,k]
//   att_text[b,t] = sum_k A [k,t] * img[b,k]
// 256 blocks = (side, c-tile of 64 cols, b-tile of 16 rows). Lanes cover
// cols -> WT loads and output stores coalesced (256 B/wave). Each wave owns
// 4 wave-UNIFORM batch rows (readfirstlane) -> x[b][k] streams through the
// scalar pipe (s_load), VMEM gets 1 load/k/wave, VALU 4 s-operand FMAs/k.
// No LDS, no atomics; K=1024 unsplit -> plain stores cover every element.
// ---------------------------------------------------------------------------
__global__ __launch_bounds__(256) void gemm_kernel(
    const float* __restrict__ A, const float* __restrict__ At,
    const float* __restrict__ img, const float* __restrict__ text,
    float* __restrict__ out)
{
    const int blk = blockIdx.x;           // 0..255
    const int side  = blk >> 7;           // 0: att_img, 1: att_text
    const int ctile = (blk >> 3) & 15;    // 16 tiles x 64 cols
    const int btile = blk & 7;            // 8 tiles x 16 rows
    const int lane  = threadIdx.x & 63;
    const int wv    = threadIdx.x >> 6;   // 0..3
    const int c = ctile * 64 + lane;
    int b0 = __builtin_amdgcn_readfirstlane(btile * 16 + wv * 4);

    const float* WT = side ? A : At;      // WT[k*1024 + c]
    const float* X  = side ? img : text;  // X[b*1024 + k]
    const float* xr0 = X + (b0 + 0) * 1024;
    const float* xr1 = X + (b0 + 1) * 1024;
    const float* xr2 = X + (b0 + 2) * 1024;
    const float* xr3 = X + (b0 + 3) * 1024;
    const float* Wc  = WT + c;

    float a0 = 0.f, a1 = 0.f, a2 = 0.f, a3 = 0.f;
    #pragma unroll 8
    for (int k = 0; k < 1024; k++) {
        float w = Wc[k * 1024];           // coalesced vector load (L2-hot)
        a0 += xr0[k] * w;                 // x*: scalar-pipe streams
        a1 += xr1[k] * w;
        a2 += xr2[k] * w;
        a3 += xr3[k] * w;
    }
    float* ob = out + side * (BD * ID) + c;
    ob[(b0 + 0) * 1024] = a0;             // coalesced stores
    ob[(b0 + 1) * 1024] = a1;
    ob[(b0 + 2) * 1024] = a2;
    ob[(b0 + 3) * 1024] = a3;
}

extern "C" void kernel_launch(void* const* d_in, const int* in_sizes, int n_in,
                              void* d_out, int out_size, void* d_ws, size_t ws_size,
                              hipStream_t stream)
{
    const float* img  = (const float*)d_in[0];   // [128,1024]
    const float* text = (const float*)d_in[1];   // [128,1024]
    const int*   src  = (const int*)  d_in[2];   // [32768]
    const int*   tgt  = (const int*)  d_in[3];   // [32768]
    const float* W1   = (const float*)d_in[4];   // [128,256]
    const float* b1   = (const float*)d_in[5];   // [128]
    const float* w2   = (const float*)d_in[6];   // [128]
    const float* b2   = (const float*)d_in[7];   // [1]
    float* out = (float*)d_out;                  // 2 x [128,1024] concat

    // workspace: 9.25 MB
    float* HimgT = (float*)d_ws;         // 131072 floats (b1 folded in)
    float* HtxtT = HimgT + 131072;       // 131072
    float* A     = HtxtT + 131072;       // 1024*1024  A[i*1024+t]
    float* At    = A + 1024 * 1024;      // 1024*1024  At[t*1024+i]

    hipMemsetAsync(A, 0, 2ull * 1024 * 1024 * sizeof(float), stream);
    h_kernel<<<256, 256, 0, stream>>>(img, text, W1, b1, HimgT, HtxtT);
    edge_kernel<<<2048, 256, 0, stream>>>(src, tgt, HimgT, HtxtT, w2, b2, A, At);
    gemm_kernel<<<256, 256, 0, stream>>>(A, At, img, text, out);
}

// Round 6
// 103.995 us; speedup vs baseline: 1.3149x; 1.3149x over previous
//
#include <hip/hip_runtime.h>
#include <math.h>

// Problem constants (fixed by the reference)
#define BD   128      // batch == hidden
#define ID   1024     // img dim
#define TD   1024     // txt dim
#define NE   32768    // edges
#define HD   128      // hidden

// ---------------------------------------------------------------------------
// K_A: H precompute. 256 blocks x 256 threads, 8 feature-rows per block.
//   HimgT[i,h] = sum_b img[b,i]*W1[h,b]       (+ b1[h] folded in)
//   HtxtT[t,h] = sum_b text[b,t]*W1[h,128+b]
// W1-side staged TRANSPOSED into LDS (stride 129, conflict-free); S-tile via
// float4. Inner loop per b: 1 conflict-free ds_read + 1 broadcast ds_read_b128
// + 4 FMA.
// ---------------------------------------------------------------------------
__global__ __launch_bounds__(256) void h_kernel(
    const float* __restrict__ img, const float* __restrict__ text,
    const float* __restrict__ W1, const float* __restrict__ b1,
    float* __restrict__ HimgT, float* __restrict__ HtxtT)
{
    __shared__ __align__(16) float Wl[64 * 129];  // 33 KB: Wl[b'*129+h]
    __shared__ __align__(16) float Sl[128 * 8];   // 4 KB:  Sl[b*8+il]
    const int blk = blockIdx.x, tid = threadIdx.x;
    const int side = blk >> 7;            // 0: img, 1: txt (128 blocks each)
    const int i0 = (blk & 127) * 8;
    const float* S = side ? text : img;
    float* Dst = side ? HtxtT : HimgT;
    const int soff = side * 128;

    {   // stage S tile: 128 rows x 8 floats = 256 float4 (coalesced)
        int b = tid >> 1, q = tid & 1;
        ((float4*)Sl)[tid] = *(const float4*)(S + b * 1024 + i0 + q * 4);
    }

    const int h = tid & 127, iq = tid >> 7;
    float acc[4] = {0.f, 0.f, 0.f, 0.f};
    #pragma unroll
    for (int half = 0; half < 2; half++) {
        __syncthreads();   // Sl ready (1st) / Wl no longer read (2nd)
        for (int idx = tid; idx < 8192; idx += 256) {
            int hh = idx >> 6, bb = idx & 63;
            Wl[bb * 129 + hh] = W1[hh * 256 + soff + half * 64 + bb];
        }
        __syncthreads();
        #pragma unroll 8
        for (int bb = 0; bb < 64; bb++) {
            int b = half * 64 + bb;
            float w = Wl[bb * 129 + h];                        // conflict-free
            float4 s4 = *(const float4*)(Sl + b * 8 + iq * 4); // broadcast
            acc[0] += s4.x * w; acc[1] += s4.y * w;
            acc[2] += s4.z * w; acc[3] += s4.w * w;
        }
    }
    float bias = side ? 0.f : b1[h];      // fold b1 into img side
    #pragma unroll
    for (int r = 0; r < 4; r++)
        Dst[(i0 + iq * 4 + r) * 128 + h] = acc[r] + bias;   // coalesced
}

// ---------------------------------------------------------------------------
// K_B: a = sigmoid(w2 . relu(HimgT[src]+HtxtT[tgt]) + b2), scattered into the
// DENSE pattern matrices: A[src,tgt] = a and At[tgt,src] = a (pre-zeroed).
// 2048 blocks x 256 thr = 8192 waves, 4 edges per wave.
// ---------------------------------------------------------------------------
__global__ __launch_bounds__(256) void edge_kernel(
    const int* __restrict__ src, const int* __restrict__ tgt,
    const float* __restrict__ HimgT, const float* __restrict__ HtxtT,
    const float* __restrict__ w2, const float* __restrict__ b2,
    float* __restrict__ A, float* __restrict__ At)
{
    const int lane = threadIdx.x & 63;
    const int wgid = blockIdx.x * 4 + (threadIdx.x >> 6);   // 0..8191
    const float w2a = w2[lane], w2b = w2[lane + 64];
    const float b2v = b2[0];
    #pragma unroll
    for (int k = 0; k < 4; k++) {
        int e = wgid * 4 + k;
        int s0 = src[e], t0 = tgt[e];
        const float* Hi = HimgT + s0 * 128;
        const float* Ht = HtxtT + t0 * 128;
        float v1 = Hi[lane]      + Ht[lane];
        float v2 = Hi[lane + 64] + Ht[lane + 64];
        float x = fmaxf(v1, 0.f) * w2a + fmaxf(v2, 0.f) * w2b;
        #pragma unroll
        for (int off = 32; off > 0; off >>= 1)
            x += __shfl_xor(x, off, 64);
        if (lane == 0) {
            float av = 1.f / (1.f + expf(-(x + b2v)));
            A [s0 * 1024 + t0] = av;      // unique (src,tgt): plain stores
            At[t0 * 1024 + s0] = av;
        }
    }
}

// ---------------------------------------------------------------------------
// K_C: dense GEMM, K-split for occupancy (R5 failure: 1 block/CU, 4 waves,
// latency-bound at 53 us on 900-cyc A/At misses).
//   att_img [b,i] = sum_k At[k,i] * text[b,k]
//   att_text[b,t] = sum_k A [k,t] * img[b,k]
// 2048 blocks: blk = btile*256 + sck, sck = (side,ctile,ksplit). The 8
// btile-sharers of one 32 KB W-strip have identical blk%8 -> same XCD
// (round-robin heuristic) -> strip fetched into ONE L2; within a block the
// strip is L1-resident for all 4 waves. 8 blocks/CU = 32 waves/CU hides
// latency. Wave = 4 uniform batch rows (scalar-pipe x streams), lanes = 64
// cols (coalesced W loads + stores). Partials atomicAdd into zeroed out.
// ---------------------------------------------------------------------------
__global__ __launch_bounds__(256) void gemm_kernel(
    const float* __restrict__ A, const float* __restrict__ At,
    const float* __restrict__ img, const float* __restrict__ text,
    float* __restrict__ out)
{
    const int blk = blockIdx.x;            // 0..2047
    const int sck   = blk & 255;           // (side, ctile, ksplit)
    const int btile = blk >> 8;            // 0..7
    const int side   = sck >> 7;           // 0: att_img, 1: att_text
    const int ctile  = (sck >> 3) & 15;    // 16 x 64 cols
    const int ksplit = sck & 7;            // 8 x 128 k
    const int lane = threadIdx.x & 63;
    const int wv   = threadIdx.x >> 6;     // 0..3
    const int c  = ctile * 64 + lane;
    const int b0 = __builtin_amdgcn_readfirstlane(btile * 16 + wv * 4);
    const int k0 = ksplit * 128;

    const float* WT = side ? A : At;       // WT[k*1024 + c]
    const float* X  = side ? img : text;   // X[b*1024 + k]
    const float* xr0 = X + (b0 + 0) * 1024 + k0;
    const float* xr1 = X + (b0 + 1) * 1024 + k0;
    const float* xr2 = X + (b0 + 2) * 1024 + k0;
    const float* xr3 = X + (b0 + 3) * 1024 + k0;
    const float* Wc  = WT + (size_t)k0 * 1024 + c;

    float a0 = 0.f, a1 = 0.f, a2 = 0.f, a3 = 0.f;
    #pragma unroll 8
    for (int k = 0; k < 128; k++) {
        float w = Wc[k * 1024];            // coalesced, L1-hot after wave 0
        a0 += xr0[k] * w;                  // x*: wave-uniform scalar streams
        a1 += xr1[k] * w;
        a2 += xr2[k] * w;
        a3 += xr3[k] * w;
    }
    float* ob = out + side * (BD * ID) + c;
    atomicAdd(&ob[(b0 + 0) * 1024], a0);   // coalesced, 8-way (per ksplit)
    atomicAdd(&ob[(b0 + 1) * 1024], a1);
    atomicAdd(&ob[(b0 + 2) * 1024], a2);
    atomicAdd(&ob[(b0 + 3) * 1024], a3);
}

extern "C" void kernel_launch(void* const* d_in, const int* in_sizes, int n_in,
                              void* d_out, int out_size, void* d_ws, size_t ws_size,
                              hipStream_t stream)
{
    const float* img  = (const float*)d_in[0];   // [128,1024]
    const float* text = (const float*)d_in[1];   // [128,1024]
    const int*   src  = (const int*)  d_in[2];   // [32768]
    const int*   tgt  = (const int*)  d_in[3];   // [32768]
    const float* W1   = (const float*)d_in[4];   // [128,256]
    const float* b1   = (const float*)d_in[5];   // [128]
    const float* w2   = (const float*)d_in[6];   // [128]
    const float* b2   = (const float*)d_in[7];   // [1]
    float* out = (float*)d_out;                  // 2 x [128,1024] concat

    // workspace: 9.25 MB
    float* HimgT = (float*)d_ws;         // 131072 floats (b1 folded in)
    float* HtxtT = HimgT + 131072;       // 131072
    float* A     = HtxtT + 131072;       // 1024*1024  A[i*1024+t]
    float* At    = A + 1024 * 1024;      // 1024*1024  At[t*1024+i]

    hipMemsetAsync(A, 0, 2ull * 1024 * 1024 * sizeof(float), stream);
    hipMemsetAsync(out, 0, (size_t)out_size * sizeof(float), stream);
    h_kernel<<<256, 256, 0, stream>>>(img, text, W1, b1, HimgT, HtxtT);
    edge_kernel<<<2048, 256, 0, stream>>>(src, tgt, HimgT, HtxtT, w2, b2, A, At);
    gemm_kernel<<<2048, 256, 0, stream>>>(A, At, img, text, out);
}

// Round 7
// 98.529 us; speedup vs baseline: 1.3879x; 1.0555x over previous
//
#include <hip/hip_runtime.h>
#include <math.h>

// Problem constants (fixed by the reference)
#define BD   128      // batch == hidden
#define NCOL 1024     // img dim == txt dim
#define NE   32768    // edges
#define CAP  128      // bucket capacity (Poisson lambda=32, max ~60; 128 safe)

// ---------------------------------------------------------------------------
// K1 "prep": two independent task groups co-scheduled in one launch:
//  blocks 0..255  : H precompute (identical to R6 h_kernel)
//    HimgT[i,h] = sum_b img[b,i]*W1[h,b] (+ b1[h]);  HtxtT likewise (txt half)
//  blocks 256..511: 32x32 tiled transposes img->imgT, text->textT
//    (needed so gather's batch-lane reads are coalesced 512 B rows)
// ---------------------------------------------------------------------------
__global__ __launch_bounds__(256) void prep_kernel(
    const float* __restrict__ img, const float* __restrict__ text,
    const float* __restrict__ W1, const float* __restrict__ b1,
    float* __restrict__ HimgT, float* __restrict__ HtxtT,
    float* __restrict__ imgT, float* __restrict__ textT)
{
    __shared__ __align__(16) float Wl[64 * 129];  // 33 KB (h) / reused (transpose)
    __shared__ __align__(16) float Sl[128 * 8];   // 4 KB (h)
    const int blk = blockIdx.x, tid = threadIdx.x;

    if (blk < 256) {
        // ---- H precompute ----
        const int side = blk >> 7;            // 0: img, 1: txt
        const int i0 = (blk & 127) * 8;
        const float* S = side ? text : img;
        float* Dst = side ? HtxtT : HimgT;
        const int soff = side * 128;

        {   // stage S tile: 128 rows x 8 floats = 256 float4 (coalesced)
            int b = tid >> 1, q = tid & 1;
            ((float4*)Sl)[tid] = *(const float4*)(S + b * 1024 + i0 + q * 4);
        }
        const int h = tid & 127, iq = tid >> 7;
        float acc[4] = {0.f, 0.f, 0.f, 0.f};
        #pragma unroll
        for (int half = 0; half < 2; half++) {
            __syncthreads();
            for (int idx = tid; idx < 8192; idx += 256) {
                int hh = idx >> 6, bb = idx & 63;
                Wl[bb * 129 + hh] = W1[hh * 256 + soff + half * 64 + bb];
            }
            __syncthreads();
            #pragma unroll 8
            for (int bb = 0; bb < 64; bb++) {
                int b = half * 64 + bb;
                float w = Wl[bb * 129 + h];                        // conflict-free
                float4 s4 = *(const float4*)(Sl + b * 8 + iq * 4); // broadcast
                acc[0] += s4.x * w; acc[1] += s4.y * w;
                acc[2] += s4.z * w; acc[3] += s4.w * w;
            }
        }
        float bias = side ? 0.f : b1[h];
        #pragma unroll
        for (int r = 0; r < 4; r++)
            Dst[(i0 + iq * 4 + r) * 128 + h] = acc[r] + bias;
    } else {
        // ---- 32x32 tiled transpose (conflict-free via +1 pad) ----
        float (*lds)[33] = (float(*)[33])Wl;     // 32*33 floats of Wl
        const int t = blk - 256;                 // 0..255
        const float* S = (t < 128) ? img : text;
        float* D = (t < 128) ? imgT : textT;
        const int tile = t & 127;                // 4 row-tiles x 32 col-tiles
        const int rt = tile >> 5, ct = tile & 31;
        const int x = tid & 31, y = tid >> 5;    // y 0..7
        #pragma unroll
        for (int k = 0; k < 4; k++) {
            int r = y + k * 8;
            lds[r][x] = S[(rt * 32 + r) * 1024 + ct * 32 + x];
        }
        __syncthreads();
        #pragma unroll
        for (int k = 0; k < 4; k++) {
            int r = y + k * 8;
            D[(ct * 32 + r) * 128 + rt * 32 + x] = lds[x][r];
        }
    }
}

// ---------------------------------------------------------------------------
// K2 "edge": a[e] = sigmoid(w2 . relu(HimgT[src]+HtxtT[tgt]) + b2), plus
// bucket fill: slot = atomicAdd(cnt[col]) -> list[col*CAP+slot] = e.
// No scan/histogram chain needed (fixed-capacity buckets).
// 2048 blocks x 256 thr = 8192 waves, 4 edges/wave.
// ---------------------------------------------------------------------------
__global__ __launch_bounds__(256) void edge_kernel(
    const int* __restrict__ src, const int* __restrict__ tgt,
    const float* __restrict__ HimgT, const float* __restrict__ HtxtT,
    const float* __restrict__ w2, const float* __restrict__ b2,
    float* __restrict__ a_e,
    int* __restrict__ cnt_src, int* __restrict__ cnt_tgt,
    int* __restrict__ list_src, int* __restrict__ list_tgt)
{
    const int lane = threadIdx.x & 63;
    const int wgid = blockIdx.x * 4 + (threadIdx.x >> 6);   // 0..8191
    const float w2a = w2[lane], w2b = w2[lane + 64];
    const float b2v = b2[0];
    #pragma unroll
    for (int k = 0; k < 4; k++) {
        int e = wgid * 4 + k;
        int s0 = src[e], t0 = tgt[e];
        const float* Hi = HimgT + s0 * 128;
        const float* Ht = HtxtT + t0 * 128;
        float v1 = Hi[lane]      + Ht[lane];
        float v2 = Hi[lane + 64] + Ht[lane + 64];
        float x = fmaxf(v1, 0.f) * w2a + fmaxf(v2, 0.f) * w2b;
        #pragma unroll
        for (int off = 32; off > 0; off >>= 1)
            x += __shfl_xor(x, off, 64);
        if (lane == 0) {
            a_e[e] = 1.f / (1.f + expf(-(x + b2v)));
            int p = atomicAdd(&cnt_src[s0], 1);
            if (p < CAP) list_src[s0 * CAP + p] = e;
            int q = atomicAdd(&cnt_tgt[t0], 1);
            if (q < CAP) list_tgt[t0 * CAP + q] = e;
        }
    }
}

// ---------------------------------------------------------------------------
// K3 "gather": atomic-free sparse contraction, one block per (side, column):
//   att_img [b,i] = sum_{e:src=i} a[e]*textT[tgt[e]*128+b]
//   att_text[b,t] = sum_{e:tgt=t} a[e]*imgT[src[e]*128+b]
// Bucket indices/coefs staged in LDS first (breaks the e->other->row
// dependency chain); then ~32 INDEPENDENT coalesced 512 B row reads (L2-hot)
// feed lane-b FMAs. Plain store covers every output element -> no memset.
// 2048 blocks x 128 thr = 8 blocks/CU, 16 waves/CU.
// ---------------------------------------------------------------------------
__global__ __launch_bounds__(128) void gather_kernel(
    const int* __restrict__ src, const int* __restrict__ tgt,
    const float* __restrict__ a_e,
    const int* __restrict__ cnt_src, const int* __restrict__ cnt_tgt,
    const int* __restrict__ list_src, const int* __restrict__ list_tgt,
    const float* __restrict__ imgT, const float* __restrict__ textT,
    float* __restrict__ out)
{
    __shared__ float avl[CAP];
    __shared__ int   ol[CAP];
    const int blk = blockIdx.x, b = threadIdx.x;
    const int side = blk >> 10, c = blk & 1023;
    int n = side ? cnt_tgt[c] : cnt_src[c];
    n = min(n, CAP);
    const int* lst = (side ? list_tgt : list_src) + c * CAP;
    const int* oth = side ? src : tgt;
    const float* T = side ? imgT : textT;

    if (b < n) {
        int e = lst[b];
        ol[b]  = oth[e];
        avl[b] = a_e[e];
    }
    __syncthreads();

    float acc = 0.f;
    for (int p = 0; p < n; p++)
        acc += avl[p] * T[ol[p] * 128 + b];   // LDS broadcast + coalesced row

    out[side * (BD * NCOL) + b * 1024 + c] = acc;
}

extern "C" void kernel_launch(void* const* d_in, const int* in_sizes, int n_in,
                              void* d_out, int out_size, void* d_ws, size_t ws_size,
                              hipStream_t stream)
{
    const float* img  = (const float*)d_in[0];   // [128,1024]
    const float* text = (const float*)d_in[1];   // [128,1024]
    const int*   src  = (const int*)  d_in[2];   // [32768]
    const int*   tgt  = (const int*)  d_in[3];   // [32768]
    const float* W1   = (const float*)d_in[4];   // [128,256]
    const float* b1   = (const float*)d_in[5];   // [128]
    const float* w2   = (const float*)d_in[6];   // [128]
    const float* b2   = (const float*)d_in[7];   // [1]
    float* out = (float*)d_out;                  // 2 x [128,1024] concat

    // workspace: ~3.3 MB
    float* HimgT   = (float*)d_ws;          // 131072 (b1 folded in)
    float* HtxtT   = HimgT + 131072;        // 131072
    float* imgT    = HtxtT + 131072;        // 131072  imgT[i*128+b]
    float* textT   = imgT  + 131072;        // 131072  textT[t*128+b]
    float* a_e     = textT + 131072;        // 32768
    int* cnt_src   = (int*)(a_e + 32768);   // 1024
    int* cnt_tgt   = cnt_src + 1024;        // 1024
    int* list_src  = cnt_tgt + 1024;        // 1024*CAP
    int* list_tgt  = list_src + 1024 * CAP; // 1024*CAP

    hipMemsetAsync(cnt_src, 0, 2 * 1024 * sizeof(int), stream);
    prep_kernel<<<512, 256, 0, stream>>>(img, text, W1, b1,
                                         HimgT, HtxtT, imgT, textT);
    edge_kernel<<<2048, 256, 0, stream>>>(src, tgt, HimgT, HtxtT, w2, b2,
                                          a_e, cnt_src, cnt_tgt,
                                          list_src, list_tgt);
    gather_kernel<<<2048, 128, 0, stream>>>(src, tgt, a_e,
                                            cnt_src, cnt_tgt,
                                            list_src, list_tgt,
                                            imgT, textT, out);
}